// Round 4
// baseline (410.936 us; speedup 1.0000x reference)
//
#include <hip/hip_runtime.h>

#define ROW_F4 192   // 768 floats = 192 float4 per output row
#define CHUNK  16    // rows per wave

typedef float v4f __attribute__((ext_vector_type(4)));

// One wave = 16 consecutive rows. Row = 192 float4 slots: slot = k*64+lane,
// k in {0,1,2}; lane<32 -> segment 2k, lane>=32 -> segment 2k+1.
//
// Tables are staged to LDS once per block so the hot loop's reads are
// ds_read_b128 (lgkmcnt) instead of global loads (vmcnt). Waiting on lgkmcnt
// does NOT force in-order drain of outstanding global stores, so the store
// stream is pure fire-and-forget like a fill kernel.
__global__ __launch_bounds__(256) void smart_embedding_kernel(
    const v4f* __restrict__ price_w,
    const v4f* __restrict__ size_w,
    const v4f* __restrict__ exchange_w,   // 4 rows  x 32 v4f
    const v4f* __restrict__ pair_w,       // 8 rows  x 32 v4f
    const v4f* __restrict__ level_w,      // 16 rows x 32 v4f
    const v4f* __restrict__ time_w,       // 32 rows x 32 v4f
    v4f* __restrict__ out,
    int rows)
{
    // LDS layout (v4f units): ex[0,128) pair[128,384) level[384,896) time[896,1920)
    __shared__ v4f lds[60 * 32];          // 30720 B
    const int tid = threadIdx.x;

    for (int s = tid; s < 60 * 32; s += 256) {
        const v4f* src;
        if (s < 128)       src = exchange_w + s;
        else if (s < 384)  src = pair_w + (s - 128);
        else if (s < 896)  src = level_w + (s - 384);
        else               src = time_w + (s - 896);
        lds[s] = *src;
    }

    const int wave = tid >> 6;
    const int lane = tid & 63;
    const int off  = lane & 31;
    const bool hi  = lane >= 32;

    // Row-invariant segment (price|size) straight from global, once.
    const v4f v0 = hi ? size_w[off] : price_w[off];

    __syncthreads();

    int r0 = (blockIdx.x * 4 + wave) * CHUNK;
    if (r0 >= rows) return;               // after the barrier — safe
    const int rend = (r0 + CHUNK < rows) ? r0 + CHUNK : rows;

    const v4f* t1 = hi ? (lds + 128) : lds;          // pair | exchange
    const v4f* t2 = hi ? (lds + 896) : (lds + 384);  // time | level
    const int p1 = hi ? 7  : 3;
    const int p2 = hi ? 31 : 15;
    int m1 = r0 % p1;                     // one-time mod, then incremental
    int m2 = r0 % p2;

    v4f* orow = out + (size_t)r0 * ROW_F4 + lane;

#pragma unroll 4
    for (int r = r0; r < rend; ++r) {
        v4f v1 = t1[m1 * 32 + off];       // ds_read_b128 (lgkmcnt only)
        v4f v2 = t2[m2 * 32 + off];
        __builtin_nontemporal_store(v0, orow);        // fire-and-forget
        __builtin_nontemporal_store(v1, orow + 64);
        __builtin_nontemporal_store(v2, orow + 128);
        orow += ROW_F4;
        m1 = (m1 + 1 == p1) ? 0 : m1 + 1;
        m2 = (m2 + 1 == p2) ? 0 : m2 + 1;
    }
}

extern "C" void kernel_launch(void* const* d_in, const int* in_sizes, int n_in,
                              void* d_out, int out_size, void* d_ws, size_t ws_size,
                              hipStream_t stream) {
    const v4f* price_w    = (const v4f*)d_in[0];
    const v4f* size_w     = (const v4f*)d_in[1];
    const v4f* exchange_w = (const v4f*)d_in[2];
    const v4f* pair_w     = (const v4f*)d_in[3];
    const v4f* level_w    = (const v4f*)d_in[4];
    const v4f* time_w     = (const v4f*)d_in[5];
    v4f* out = (v4f*)d_out;

    const int rows = out_size / 768;                          // = num_features
    const int blocks = (rows + 4 * CHUNK - 1) / (4 * CHUNK);  // 4 waves/block

    smart_embedding_kernel<<<blocks, 256, 0, stream>>>(
        price_w, size_w, exchange_w, pair_w, level_w, time_w, out, rows);
}